// Round 11
// baseline (296.324 us; speedup 1.0000x reference)
//
#include <hip/hip_runtime.h>
#include <stdint.h>

#define NN 50000
#define DD 128
#define EE 800000
#define LN_EPS 1e-5f
#define SCAN_BLOCKS ((NN + 255) / 256)   // 196
#define ROWS 32                          // nodes per fused block
#define ASTRIDE 136                      // LDS A stride in bf16 elems

#define CH 256                           // edge chunks (one block each)
#define EC (EE / CH)                     // 3125 edges/chunk
#define NP8 50000                        // bytes per chunk hist (u8 per node)
#define NW (NP8 / 4)                     // 12500 u32 words

typedef __attribute__((ext_vector_type(8))) short bf8_t;   // 8 bf16 (MFMA A/B frag)
typedef __attribute__((ext_vector_type(4))) float f32x4;   // MFMA C/D frag

// round-to-nearest-even fp32 -> bf16 bits
static __device__ __forceinline__ unsigned short f2bf(float f) {
    unsigned u = __float_as_uint(f);
    u += 0x7FFFu + ((u >> 16) & 1u);
    return (unsigned short)(u >> 16);
}

#define BF16ACC(u) do { \
    acc[0] += __uint_as_float((u).x << 16); \
    acc[1] += __uint_as_float((u).x & 0xffff0000u); \
    acc[2] += __uint_as_float((u).y << 16); \
    acc[3] += __uint_as_float((u).y & 0xffff0000u); \
    acc[4] += __uint_as_float((u).z << 16); \
    acc[5] += __uint_as_float((u).z & 0xffff0000u); \
    acc[6] += __uint_as_float((u).w << 16); \
    acc[7] += __uint_as_float((u).w & 0xffff0000u); \
} while (0)

// ---------------- chunk histograms: u8 packed, full node range in ONE LDS phase ----------------
__global__ __launch_bounds__(256) void hist_kernel(
    const int* __restrict__ src, const int* __restrict__ dst,
    unsigned char* __restrict__ epos8,
    unsigned int* __restrict__ histI, unsigned int* __restrict__ histO) {
    __shared__ unsigned int lh[NW];   // 50 KB
    int tid = threadIdx.x;
    int c = blockIdx.x;
    int e0 = c * EC, e1 = e0 + EC;

    // phase A: in-degree (dst) + epos
    for (int w = tid; w < NW; w += 256) lh[w] = 0;
    __syncthreads();
    for (int e = e0 + tid; e < e1; e += 256) {
        int d = dst[e];
        int f = (d & 3) * 8;
        unsigned old = atomicAdd(&lh[d >> 2], 1u << f);
        epos8[e] = (unsigned char)(old >> f);
    }
    __syncthreads();
    {
        unsigned int* o = histI + (size_t)c * NW;
        for (int w = tid; w < NW; w += 256) o[w] = lh[w];
    }
    __syncthreads();

    // phase B: out-degree (src)
    for (int w = tid; w < NW; w += 256) lh[w] = 0;
    __syncthreads();
    for (int e = e0 + tid; e < e1; e += 256) {
        int d = src[e];
        atomicAdd(&lh[d >> 2], 1u << ((d & 3) * 8));
    }
    __syncthreads();
    {
        unsigned int* o = histO + (size_t)c * NW;
        for (int w = tid; w < NW; w += 256) o[w] = lh[w];
    }
}

// ---------------- sum chunk hists -> cntI/choff(in-place)/iso/isi/bsum ----------------
__global__ __launch_bounds__(256) void sum_kernel(
    unsigned char* __restrict__ histI8,          // in-place -> choff8
    const unsigned char* __restrict__ histO8,
    int* __restrict__ cntI, float* __restrict__ iso, float* __restrict__ isi,
    int* __restrict__ bsum) {
    __shared__ int s[256];
    int tid = threadIdx.x;
    int n = blockIdx.x * 256 + tid;

    int ci = 0, co = 0;
    if (n < NN) {
#pragma unroll 8
        for (int c = 0; c < CH; c++) {
            size_t idx = (size_t)c * NP8 + n;
            unsigned char v = histI8[idx];
            histI8[idx] = (unsigned char)ci;   // choff8[c][n] = prefix (max in-deg << 256)
            ci += v;
            co += histO8[idx];
        }
        iso[n] = rsqrtf(fmaxf((float)co, 1.0f));
        isi[n] = rsqrtf(fmaxf((float)ci, 1.0f));
        cntI[n] = ci;
    }
    s[tid] = (n < NN) ? ci : 0;
    __syncthreads();
    for (int off = 128; off > 0; off >>= 1) {
        if (tid < off) s[tid] += s[tid + off];
        __syncthreads();
    }
    if (tid == 0) bsum[blockIdx.x] = s[0];
}

// ---------------- rowptr (local bsum prefix) + feature cast (hb1 = bf16(feat*iso)) ----------------
__global__ __launch_bounds__(256) void scanC_kernel(
    const int* __restrict__ cnt, const int* __restrict__ bsum,
    int* __restrict__ rowptr,
    const float* __restrict__ feat, const float* __restrict__ iso,
    unsigned short* __restrict__ hb) {
    __shared__ int s[256];
    __shared__ int base_s;
    __shared__ float iso_s[256];
    int tid = threadIdx.x;
    int i = blockIdx.x * 256 + tid;

    int bv = (tid < SCAN_BLOCKS && tid < blockIdx.x) ? bsum[tid] : 0;
    s[tid] = bv;
    __syncthreads();
    for (int off = 128; off > 0; off >>= 1) {
        if (tid < off) s[tid] += s[tid + off];
        __syncthreads();
    }
    if (tid == 0) base_s = s[0];
    __syncthreads();
    int base = base_s;

    iso_s[tid] = (i < NN) ? iso[i] : 1.f;
    __syncthreads();

    int v = (i < NN) ? cnt[i] : 0;
    s[tid] = v;
    __syncthreads();
    for (int off = 1; off < 256; off <<= 1) {
        int t = (tid >= off) ? s[tid - off] : 0;
        __syncthreads();
        s[tid] += t;
        __syncthreads();
    }
    if (i < NN) rowptr[i] = base + s[tid] - v;  // exclusive
    if (blockIdx.x == 0 && tid == 0) rowptr[NN] = EE;

    // cast this block's 256 rows: 8 rows x 32 lanes (coalesced float4)
    int rr = tid >> 5;
    int q = tid & 31;
    int row0 = blockIdx.x * 256;
#pragma unroll 4
    for (int it = 0; it < 32; it++) {
        int r = it * 8 + rr;
        int row = row0 + r;
        if (row < NN) {
            float sc = iso_s[r];
            float4 fv = ((const float4*)feat)[(size_t)row * 32 + q];
            ushort4 o;
            o.x = f2bf(fv.x * sc); o.y = f2bf(fv.y * sc);
            o.z = f2bf(fv.z * sc); o.w = f2bf(fv.w * sc);
            ((ushort4*)hb)[(size_t)row * 32 + q] = o;
        }
    }
}

// ---------------- CSR fill (deterministic, atomic-free) + W transpose/cast ----------------
__global__ void fill_kernel(const int* __restrict__ src, const int* __restrict__ dst,
                            const unsigned char* __restrict__ epos8,
                            const unsigned char* __restrict__ choff8,
                            const int* __restrict__ rowptr, int* __restrict__ csr,
                            const float* __restrict__ W1, const float* __restrict__ W2,
                            unsigned short* __restrict__ wbt1, unsigned short* __restrict__ wbt2) {
    int e = blockIdx.x * blockDim.x + threadIdx.x;
    if (e < EE) {
        int d = dst[e];
        int c = e / EC;
        int pos = rowptr[d] + (int)choff8[(size_t)c * NP8 + d] + (int)epos8[e];
        csr[pos] = src[e];
    }
    // first 128 blocks also produce wbt[n][k] = bf16(W[k][n])
    if (blockIdx.x < 128) {
        int idx = (blockIdx.x & 63) * 256 + threadIdx.x;   // 0..16383 = k*128+n
        const float* W = (blockIdx.x < 64) ? W1 : W2;
        unsigned short* wt = (blockIdx.x < 64) ? wbt1 : wbt2;
        int k = idx >> 7, n = idx & 127;
        wt[n * 128 + k] = f2bf(W[idx]);
    }
}

// ---------------- fused: gather(bf16) -> bf16 LDS -> MFMA GEMM -> LN -> ReLU ----------------
// __launch_bounds__(256, 8): 8 waves/EU -> 8 blocks/CU (VGPR cap 64; measured 52).
// Round-10 counters showed 29% occupancy with a latency-bound gather — TLP is the lever.
template <int OUTMODE>
__global__ __launch_bounds__(256, 8) void fused_layer(
    const unsigned short* __restrict__ hb, const int* __restrict__ csr,
    const int* __restrict__ rowptr, const float* __restrict__ isi,
    const float* __restrict__ iso,
    const unsigned short* __restrict__ wbt, const float* __restrict__ b,
    const float* __restrict__ g, const float* __restrict__ be,
    float* __restrict__ outf, unsigned short* __restrict__ outb) {
    __shared__ unsigned short Asb[ROWS][ASTRIDE];   // 8704 B
    __shared__ float redS[4][16], redSS[4][16];     // 512 B

    int tid = threadIdx.x;
    int node0 = blockIdx.x * ROWS;
    int w = tid >> 6;            // wave 0..3
    int lane = tid & 63;
    int quad = lane >> 4;        // 0..3
    int l = lane & 15;           // 0..15

    // ---- phase 1: gather ----
    {
        int sub = (tid >> 4) & 3;
#pragma unroll
        for (int p = 0; p < 2; p++) {
            int r = w * 8 + p * 4 + sub;
            int n = node0 + r;
            float acc[8];
#pragma unroll
            for (int i = 0; i < 8; i++) acc[i] = 0.f;
            if (n < NN) {
                int beg = rowptr[n];
                int end = rowptr[n + 1];
                int j = beg;
                for (; j + 7 < end; j += 8) {
                    int s0 = csr[j];     int s1 = csr[j + 1];
                    int s2 = csr[j + 2]; int s3 = csr[j + 3];
                    int s4 = csr[j + 4]; int s5 = csr[j + 5];
                    int s6 = csr[j + 6]; int s7 = csr[j + 7];
                    uint4 u0 = ((const uint4*)(hb + (size_t)s0 * DD))[l];
                    uint4 u1 = ((const uint4*)(hb + (size_t)s1 * DD))[l];
                    uint4 u2 = ((const uint4*)(hb + (size_t)s2 * DD))[l];
                    uint4 u3 = ((const uint4*)(hb + (size_t)s3 * DD))[l];
                    uint4 u4 = ((const uint4*)(hb + (size_t)s4 * DD))[l];
                    uint4 u5 = ((const uint4*)(hb + (size_t)s5 * DD))[l];
                    uint4 u6 = ((const uint4*)(hb + (size_t)s6 * DD))[l];
                    uint4 u7 = ((const uint4*)(hb + (size_t)s7 * DD))[l];
                    BF16ACC(u0); BF16ACC(u1); BF16ACC(u2); BF16ACC(u3);
                    BF16ACC(u4); BF16ACC(u5); BF16ACC(u6); BF16ACC(u7);
                }
                for (; j < end; j++) {
                    int s0 = csr[j];
                    uint4 u0 = ((const uint4*)(hb + (size_t)s0 * DD))[l];
                    BF16ACC(u0);
                }
            }
            uint4 pk;
            pk.x = (unsigned)f2bf(acc[0]) | ((unsigned)f2bf(acc[1]) << 16);
            pk.y = (unsigned)f2bf(acc[2]) | ((unsigned)f2bf(acc[3]) << 16);
            pk.z = (unsigned)f2bf(acc[4]) | ((unsigned)f2bf(acc[5]) << 16);
            pk.w = (unsigned)f2bf(acc[6]) | ((unsigned)f2bf(acc[7]) << 16);
            *(uint4*)&Asb[r][l * 8] = pk;
        }
    }
    __syncthreads();

    // ---- phase 2: MFMA GEMM ----
    int rt = w & 1;              // row tile (16 rows)
    int ch = w >> 1;             // column half (64 cols)

    bf8_t af[4];
#pragma unroll
    for (int kb = 0; kb < 4; kb++)
        af[kb] = *(bf8_t*)&Asb[rt * 16 + l][kb * 32 + quad * 8];

    f32x4 acc[4];
#pragma unroll
    for (int tc = 0; tc < 4; tc++) acc[tc] = (f32x4){0.f, 0.f, 0.f, 0.f};

#pragma unroll
    for (int tc = 0; tc < 4; tc++) {
        int n = ch * 64 + tc * 16 + l;   // output column
#pragma unroll
        for (int kb = 0; kb < 4; kb++) {
            bf8_t bfr = *(const bf8_t*)&wbt[(size_t)n * 128 + kb * 32 + quad * 8];
            acc[tc] = __builtin_amdgcn_mfma_f32_16x16x32_bf16(af[kb], bfr, acc[tc], 0, 0, 0);
        }
    }

    // ---- epilogue: *isi, +b, LN, ReLU, store ----
    float bb[4], ggv[4], bev[4];
    int cbase = ch * 64 + l;
#pragma unroll
    for (int tc = 0; tc < 4; tc++) {
        int c = cbase + tc * 16;
        bb[tc] = b[c]; ggv[tc] = g[c]; bev[tc] = be[c];
    }

    float s[4], ss[4];
#pragma unroll
    for (int i = 0; i < 4; i++) {
        int n = node0 + rt * 16 + quad * 4 + i;
        float isin = (n < NN) ? isi[n] : 1.f;
        s[i] = 0.f; ss[i] = 0.f;
#pragma unroll
        for (int tc = 0; tc < 4; tc++) {
            float v = acc[tc][i] * isin + bb[tc];
            acc[tc][i] = v;
            s[i] += v; ss[i] += v * v;
        }
    }
#pragma unroll
    for (int i = 0; i < 4; i++) {
#pragma unroll
        for (int m = 1; m <= 8; m <<= 1) {
            s[i] += __shfl_xor(s[i], m);
            ss[i] += __shfl_xor(ss[i], m);
        }
    }
    if (l == 0) {
#pragma unroll
        for (int i = 0; i < 4; i++) {
            redS[w][quad * 4 + i] = s[i];
            redSS[w][quad * 4 + i] = ss[i];
        }
    }
    __syncthreads();

#pragma unroll
    for (int i = 0; i < 4; i++) {
        int r = quad * 4 + i;
        float S  = redS[w][r]  + redS[w ^ 2][r];
        float SS = redSS[w][r] + redSS[w ^ 2][r];
        float mu = S * (1.f / 128.f);
        float var = SS * (1.f / 128.f) - mu * mu;
        float rstd = rsqrtf(var + LN_EPS);
        int n = node0 + rt * 16 + r;
        if (n < NN) {
            float isov = (OUTMODE == 1) ? iso[n] : 0.f;
            size_t base = (size_t)n * DD;
#pragma unroll
            for (int tc = 0; tc < 4; tc++) {
                float o = fmaxf((acc[tc][i] - mu) * rstd * ggv[tc] + bev[tc], 0.f);
                int c = cbase + tc * 16;
                if (OUTMODE == 0) {
                    outf[base + c] = o;
                } else {
                    outb[base + c] = f2bf(o * isov);
                }
            }
        }
    }
}

static inline char* alignp(char* p, size_t a) {
    return (char*)(((uintptr_t)p + a - 1) & ~(uintptr_t)(a - 1));
}

extern "C" void kernel_launch(void* const* d_in, const int* in_sizes, int n_in,
                              void* d_out, int out_size, void* d_ws, size_t ws_size,
                              hipStream_t stream) {
    const float* features = (const float*)d_in[0];
    const int*   src      = (const int*)d_in[1];
    const int*   dst      = (const int*)d_in[2];
    const float* W1  = (const float*)d_in[3];
    const float* b1  = (const float*)d_in[4];
    const float* g1  = (const float*)d_in[5];
    const float* be1 = (const float*)d_in[6];
    const float* W2  = (const float*)d_in[7];
    const float* b2  = (const float*)d_in[8];
    const float* g2  = (const float*)d_in[9];
    const float* be2 = (const float*)d_in[10];
    float* out = (float*)d_out;

    // workspace layout (256B-aligned slices)
    char* p = (char*)d_ws;
    int* cntI = (int*)p;                 p = alignp(p + NN * 4, 256);
    int* rowptr = (int*)p;               p = alignp(p + (NN + 1) * 4, 256);
    int* bsum = (int*)p;                 p = alignp(p + SCAN_BLOCKS * 4, 256);
    int* csr = (int*)p;                  p = alignp(p + (size_t)EE * 4, 256);
    float* iso = (float*)p;              p = alignp(p + NN * 4, 256);
    float* isi = (float*)p;              p = alignp(p + NN * 4, 256);
    unsigned short* hb1 = (unsigned short*)p;  p = alignp(p + (size_t)NN * DD * 2, 256);
    unsigned short* hb2 = (unsigned short*)p;  p = alignp(p + (size_t)NN * DD * 2, 256);
    unsigned short* wbt1 = (unsigned short*)p; p = alignp(p + DD * DD * 2, 256);
    unsigned short* wbt2 = (unsigned short*)p; p = alignp(p + DD * DD * 2, 256);
    unsigned char* epos8 = (unsigned char*)p;  p = alignp(p + EE, 256);

    // Aliases (CH*NP8 = 256*50000 = 12,800,000 B = exactly NN*DD*2):
    //  histI8 -> hb2: choff dead after fill_kernel; fused<1> writes hb2 after fill.  OK
    //  histO8 -> hb1: histO dead after sum_kernel; scanC writes hb1 (cast) after sum. OK
    unsigned char* histI8 = (unsigned char*)hb2;
    unsigned char* histO8 = (unsigned char*)hb1;

    hist_kernel<<<CH, 256, 0, stream>>>(src, dst, epos8,
                                        (unsigned int*)histI8, (unsigned int*)histO8);
    sum_kernel<<<SCAN_BLOCKS, 256, 0, stream>>>(histI8, histO8, cntI, iso, isi, bsum);
    scanC_kernel<<<SCAN_BLOCKS, 256, 0, stream>>>(cntI, bsum, rowptr, features, iso, hb1);
    fill_kernel<<<(EE + 255) / 256, 256, 0, stream>>>(src, dst, epos8, histI8,
                                                      rowptr, csr, W1, W2, wbt1, wbt2);

    const int fblocks = (NN + ROWS - 1) / ROWS;  // 1563
    // layer 1: hb1 -> hb2 (bf16, iso-prescaled)
    fused_layer<1><<<fblocks, 256, 0, stream>>>(hb1, csr, rowptr, isi, iso,
                                                wbt1, b1, g1, be1, nullptr, hb2);
    // layer 2: hb2 -> out (fp32)
    fused_layer<0><<<fblocks, 256, 0, stream>>>(hb2, csr, rowptr, isi, iso,
                                                wbt2, b2, g2, be2, out, nullptr);
}

// Round 12
// 255.326 us; speedup vs baseline: 1.1606x; 1.1606x over previous
//
#include <hip/hip_runtime.h>
#include <stdint.h>

#define NN 50000
#define DD 128
#define EE 800000
#define LN_EPS 1e-5f
#define SCAN_BLOCKS ((NN + 255) / 256)   // 196
#define ROWS 16                          // nodes per fused block (50000 = 3125 * 16 exactly)
#define ASTRIDE 136                      // LDS A stride in bf16 elems

#define CH 256                           // edge chunks (one block each)
#define EC (EE / CH)                     // 3125 edges/chunk
#define NP8 50000                        // bytes per chunk hist (u8 per node)
#define NW (NP8 / 4)                     // 12500 u32 words

typedef __attribute__((ext_vector_type(8))) short bf8_t;   // 8 bf16 (MFMA A/B frag)
typedef __attribute__((ext_vector_type(4))) float f32x4;   // MFMA C/D frag

// round-to-nearest-even fp32 -> bf16 bits
static __device__ __forceinline__ unsigned short f2bf(float f) {
    unsigned u = __float_as_uint(f);
    u += 0x7FFFu + ((u >> 16) & 1u);
    return (unsigned short)(u >> 16);
}

#define BF16ACC(u) do { \
    acc[0] += __uint_as_float((u).x << 16); \
    acc[1] += __uint_as_float((u).x & 0xffff0000u); \
    acc[2] += __uint_as_float((u).y << 16); \
    acc[3] += __uint_as_float((u).y & 0xffff0000u); \
    acc[4] += __uint_as_float((u).z << 16); \
    acc[5] += __uint_as_float((u).z & 0xffff0000u); \
    acc[6] += __uint_as_float((u).w << 16); \
    acc[7] += __uint_as_float((u).w & 0xffff0000u); \
} while (0)

// ---------------- chunk histograms: u8 packed, full node range in ONE LDS phase ----------------
__global__ __launch_bounds__(256) void hist_kernel(
    const int* __restrict__ src, const int* __restrict__ dst,
    unsigned char* __restrict__ epos8,
    unsigned int* __restrict__ histI, unsigned int* __restrict__ histO) {
    __shared__ unsigned int lh[NW];   // 50 KB
    int tid = threadIdx.x;
    int c = blockIdx.x;
    int e0 = c * EC, e1 = e0 + EC;

    // phase A: in-degree (dst) + epos
    for (int w = tid; w < NW; w += 256) lh[w] = 0;
    __syncthreads();
    for (int e = e0 + tid; e < e1; e += 256) {
        int d = dst[e];
        int f = (d & 3) * 8;
        unsigned old = atomicAdd(&lh[d >> 2], 1u << f);
        epos8[e] = (unsigned char)(old >> f);
    }
    __syncthreads();
    {
        unsigned int* o = histI + (size_t)c * NW;
        for (int w = tid; w < NW; w += 256) o[w] = lh[w];
    }
    __syncthreads();

    // phase B: out-degree (src)
    for (int w = tid; w < NW; w += 256) lh[w] = 0;
    __syncthreads();
    for (int e = e0 + tid; e < e1; e += 256) {
        int d = src[e];
        atomicAdd(&lh[d >> 2], 1u << ((d & 3) * 8));
    }
    __syncthreads();
    {
        unsigned int* o = histO + (size_t)c * NW;
        for (int w = tid; w < NW; w += 256) o[w] = lh[w];
    }
}

// ---------------- sum chunk hists -> cntI/choff(in-place)/iso/isi/bsum ----------------
__global__ __launch_bounds__(256) void sum_kernel(
    unsigned char* __restrict__ histI8,          // in-place -> choff8
    const unsigned char* __restrict__ histO8,
    int* __restrict__ cntI, float* __restrict__ iso, float* __restrict__ isi,
    int* __restrict__ bsum) {
    __shared__ int s[256];
    int tid = threadIdx.x;
    int n = blockIdx.x * 256 + tid;

    int ci = 0, co = 0;
    if (n < NN) {
#pragma unroll 8
        for (int c = 0; c < CH; c++) {
            size_t idx = (size_t)c * NP8 + n;
            unsigned char v = histI8[idx];
            histI8[idx] = (unsigned char)ci;   // choff8[c][n] = prefix (max in-deg << 256)
            ci += v;
            co += histO8[idx];
        }
        iso[n] = rsqrtf(fmaxf((float)co, 1.0f));
        isi[n] = rsqrtf(fmaxf((float)ci, 1.0f));
        cntI[n] = ci;
    }
    s[tid] = (n < NN) ? ci : 0;
    __syncthreads();
    for (int off = 128; off > 0; off >>= 1) {
        if (tid < off) s[tid] += s[tid + off];
        __syncthreads();
    }
    if (tid == 0) bsum[blockIdx.x] = s[0];
}

// ---------------- rowptr (local bsum prefix) + feature cast (hb1 = bf16(feat*iso)) ----------------
__global__ __launch_bounds__(256) void scanC_kernel(
    const int* __restrict__ cnt, const int* __restrict__ bsum,
    int* __restrict__ rowptr,
    const float* __restrict__ feat, const float* __restrict__ iso,
    unsigned short* __restrict__ hb) {
    __shared__ int s[256];
    __shared__ int base_s;
    __shared__ float iso_s[256];
    int tid = threadIdx.x;
    int i = blockIdx.x * 256 + tid;

    int bv = (tid < SCAN_BLOCKS && tid < blockIdx.x) ? bsum[tid] : 0;
    s[tid] = bv;
    __syncthreads();
    for (int off = 128; off > 0; off >>= 1) {
        if (tid < off) s[tid] += s[tid + off];
        __syncthreads();
    }
    if (tid == 0) base_s = s[0];
    __syncthreads();
    int base = base_s;

    iso_s[tid] = (i < NN) ? iso[i] : 1.f;
    __syncthreads();

    int v = (i < NN) ? cnt[i] : 0;
    s[tid] = v;
    __syncthreads();
    for (int off = 1; off < 256; off <<= 1) {
        int t = (tid >= off) ? s[tid - off] : 0;
        __syncthreads();
        s[tid] += t;
        __syncthreads();
    }
    if (i < NN) rowptr[i] = base + s[tid] - v;  // exclusive
    if (blockIdx.x == 0 && tid == 0) rowptr[NN] = EE;

    // cast this block's 256 rows: 8 rows x 32 lanes (coalesced float4)
    int rr = tid >> 5;
    int q = tid & 31;
    int row0 = blockIdx.x * 256;
#pragma unroll 4
    for (int it = 0; it < 32; it++) {
        int r = it * 8 + rr;
        int row = row0 + r;
        if (row < NN) {
            float sc = iso_s[r];
            float4 fv = ((const float4*)feat)[(size_t)row * 32 + q];
            ushort4 o;
            o.x = f2bf(fv.x * sc); o.y = f2bf(fv.y * sc);
            o.z = f2bf(fv.z * sc); o.w = f2bf(fv.w * sc);
            ((ushort4*)hb)[(size_t)row * 32 + q] = o;
        }
    }
}

// ---------------- CSR fill (deterministic, atomic-free) + W transpose/cast ----------------
__global__ void fill_kernel(const int* __restrict__ src, const int* __restrict__ dst,
                            const unsigned char* __restrict__ epos8,
                            const unsigned char* __restrict__ choff8,
                            const int* __restrict__ rowptr, int* __restrict__ csr,
                            const float* __restrict__ W1, const float* __restrict__ W2,
                            unsigned short* __restrict__ wbt1, unsigned short* __restrict__ wbt2) {
    int e = blockIdx.x * blockDim.x + threadIdx.x;
    if (e < EE) {
        int d = dst[e];
        int c = e / EC;
        int pos = rowptr[d] + (int)choff8[(size_t)c * NP8 + d] + (int)epos8[e];
        csr[pos] = src[e];
    }
    // first 128 blocks also produce wbt[n][k] = bf16(W[k][n])
    if (blockIdx.x < 128) {
        int idx = (blockIdx.x & 63) * 256 + threadIdx.x;   // 0..16383 = k*128+n
        const float* W = (blockIdx.x < 64) ? W1 : W2;
        unsigned short* wt = (blockIdx.x < 64) ? wbt1 : wbt2;
        int k = idx >> 7, n = idx & 127;
        wt[n * 128 + k] = f2bf(W[idx]);
    }
}

// ---------------- fused: gather(bf16) -> bf16 LDS -> MFMA GEMM -> LN -> ReLU ----------------
// ROWS=16, 3125 blocks (~12/CU): finer block granularity to absorb degree-imbalance
// stragglers (round-10 showed 29% time-avg occupancy at 1563 blocks). No min-waves
// bound (round-11: (256,8) forced VGPR 32 -> scratch spills -> 76 MB WRITE_SIZE).
// Gather: 16 subgroups x 16 lanes, one row each. MFMA: one 16-row tile; wave w owns
// 32 cols (2 x 16-col tiles). LN: 4-wave partial sum via LDS.
template <int OUTMODE>
__global__ __launch_bounds__(256) void fused_layer(
    const unsigned short* __restrict__ hb, const int* __restrict__ csr,
    const int* __restrict__ rowptr, const float* __restrict__ isi,
    const float* __restrict__ iso,
    const unsigned short* __restrict__ wbt, const float* __restrict__ b,
    const float* __restrict__ g, const float* __restrict__ be,
    float* __restrict__ outf, unsigned short* __restrict__ outb) {
    __shared__ unsigned short Asb[ROWS][ASTRIDE];   // 4352 B
    __shared__ float redS[4][16], redSS[4][16];     // 512 B

    int tid = threadIdx.x;
    int node0 = blockIdx.x * ROWS;
    int w = tid >> 6;            // wave 0..3
    int lane = tid & 63;
    int quad = lane >> 4;        // 0..3
    int l = lane & 15;           // 0..15

    // ---- phase 1: gather (subgroup tid>>4 owns row tid>>4) ----
    {
        int r = tid >> 4;        // 0..15
        int n = node0 + r;
        float acc[8];
#pragma unroll
        for (int i = 0; i < 8; i++) acc[i] = 0.f;
        int beg = rowptr[n];
        int end = rowptr[n + 1];
        int j = beg;
        for (; j + 7 < end; j += 8) {
            int s0 = csr[j];     int s1 = csr[j + 1];
            int s2 = csr[j + 2]; int s3 = csr[j + 3];
            int s4 = csr[j + 4]; int s5 = csr[j + 5];
            int s6 = csr[j + 6]; int s7 = csr[j + 7];
            uint4 u0 = ((const uint4*)(hb + (size_t)s0 * DD))[l];
            uint4 u1 = ((const uint4*)(hb + (size_t)s1 * DD))[l];
            uint4 u2 = ((const uint4*)(hb + (size_t)s2 * DD))[l];
            uint4 u3 = ((const uint4*)(hb + (size_t)s3 * DD))[l];
            uint4 u4 = ((const uint4*)(hb + (size_t)s4 * DD))[l];
            uint4 u5 = ((const uint4*)(hb + (size_t)s5 * DD))[l];
            uint4 u6 = ((const uint4*)(hb + (size_t)s6 * DD))[l];
            uint4 u7 = ((const uint4*)(hb + (size_t)s7 * DD))[l];
            BF16ACC(u0); BF16ACC(u1); BF16ACC(u2); BF16ACC(u3);
            BF16ACC(u4); BF16ACC(u5); BF16ACC(u6); BF16ACC(u7);
        }
        for (; j < end; j++) {
            int s0 = csr[j];
            uint4 u0 = ((const uint4*)(hb + (size_t)s0 * DD))[l];
            BF16ACC(u0);
        }
        uint4 pk;
        pk.x = (unsigned)f2bf(acc[0]) | ((unsigned)f2bf(acc[1]) << 16);
        pk.y = (unsigned)f2bf(acc[2]) | ((unsigned)f2bf(acc[3]) << 16);
        pk.z = (unsigned)f2bf(acc[4]) | ((unsigned)f2bf(acc[5]) << 16);
        pk.w = (unsigned)f2bf(acc[6]) | ((unsigned)f2bf(acc[7]) << 16);
        *(uint4*)&Asb[r][l * 8] = pk;
    }
    __syncthreads();

    // ---- phase 2: MFMA GEMM (16 rows x 128 cols; wave w -> cols [w*32, w*32+32)) ----
    bf8_t af[4];
#pragma unroll
    for (int kb = 0; kb < 4; kb++)
        af[kb] = *(bf8_t*)&Asb[l][kb * 32 + quad * 8];

    f32x4 acc[2];
#pragma unroll
    for (int tc = 0; tc < 2; tc++) acc[tc] = (f32x4){0.f, 0.f, 0.f, 0.f};

#pragma unroll
    for (int tc = 0; tc < 2; tc++) {
        int n = w * 32 + tc * 16 + l;   // output column
#pragma unroll
        for (int kb = 0; kb < 4; kb++) {
            bf8_t bfr = *(const bf8_t*)&wbt[(size_t)n * 128 + kb * 32 + quad * 8];
            acc[tc] = __builtin_amdgcn_mfma_f32_16x16x32_bf16(af[kb], bfr, acc[tc], 0, 0, 0);
        }
    }

    // ---- epilogue: *isi, +b, LN, ReLU, store ----
    float bb[2], ggv[2], bev[2];
    int cbase = w * 32 + l;
#pragma unroll
    for (int tc = 0; tc < 2; tc++) {
        int c = cbase + tc * 16;
        bb[tc] = b[c]; ggv[tc] = g[c]; bev[tc] = be[c];
    }

    float s[4], ss[4];
#pragma unroll
    for (int i = 0; i < 4; i++) {
        int n = node0 + quad * 4 + i;
        float isin = isi[n];
        s[i] = 0.f; ss[i] = 0.f;
#pragma unroll
        for (int tc = 0; tc < 2; tc++) {
            float v = acc[tc][i] * isin + bb[tc];
            acc[tc][i] = v;
            s[i] += v; ss[i] += v * v;
        }
    }
#pragma unroll
    for (int i = 0; i < 4; i++) {
#pragma unroll
        for (int m = 1; m <= 8; m <<= 1) {
            s[i] += __shfl_xor(s[i], m);
            ss[i] += __shfl_xor(ss[i], m);
        }
    }
    if (l == 0) {
#pragma unroll
        for (int i = 0; i < 4; i++) {
            redS[w][quad * 4 + i] = s[i];
            redSS[w][quad * 4 + i] = ss[i];
        }
    }
    __syncthreads();

#pragma unroll
    for (int i = 0; i < 4; i++) {
        int r = quad * 4 + i;
        float S  = redS[0][r] + redS[1][r] + redS[2][r] + redS[3][r];
        float SS = redSS[0][r] + redSS[1][r] + redSS[2][r] + redSS[3][r];
        float mu = S * (1.f / 128.f);
        float var = SS * (1.f / 128.f) - mu * mu;
        float rstd = rsqrtf(var + LN_EPS);
        int n = node0 + r;
        float isov = (OUTMODE == 1) ? iso[n] : 0.f;
        size_t base = (size_t)n * DD;
#pragma unroll
        for (int tc = 0; tc < 2; tc++) {
            float o = fmaxf((acc[tc][i] - mu) * rstd * ggv[tc] + bev[tc], 0.f);
            int c = cbase + tc * 16;
            if (OUTMODE == 0) {
                outf[base + c] = o;
            } else {
                outb[base + c] = f2bf(o * isov);
            }
        }
    }
}

static inline char* alignp(char* p, size_t a) {
    return (char*)(((uintptr_t)p + a - 1) & ~(uintptr_t)(a - 1));
}

extern "C" void kernel_launch(void* const* d_in, const int* in_sizes, int n_in,
                              void* d_out, int out_size, void* d_ws, size_t ws_size,
                              hipStream_t stream) {
    const float* features = (const float*)d_in[0];
    const int*   src      = (const int*)d_in[1];
    const int*   dst      = (const int*)d_in[2];
    const float* W1  = (const float*)d_in[3];
    const float* b1  = (const float*)d_in[4];
    const float* g1  = (const float*)d_in[5];
    const float* be1 = (const float*)d_in[6];
    const float* W2  = (const float*)d_in[7];
    const float* b2  = (const float*)d_in[8];
    const float* g2  = (const float*)d_in[9];
    const float* be2 = (const float*)d_in[10];
    float* out = (float*)d_out;

    // workspace layout (256B-aligned slices)
    char* p = (char*)d_ws;
    int* cntI = (int*)p;                 p = alignp(p + NN * 4, 256);
    int* rowptr = (int*)p;               p = alignp(p + (NN + 1) * 4, 256);
    int* bsum = (int*)p;                 p = alignp(p + SCAN_BLOCKS * 4, 256);
    int* csr = (int*)p;                  p = alignp(p + (size_t)EE * 4, 256);
    float* iso = (float*)p;              p = alignp(p + NN * 4, 256);
    float* isi = (float*)p;              p = alignp(p + NN * 4, 256);
    unsigned short* hb1 = (unsigned short*)p;  p = alignp(p + (size_t)NN * DD * 2, 256);
    unsigned short* hb2 = (unsigned short*)p;  p = alignp(p + (size_t)NN * DD * 2, 256);
    unsigned short* wbt1 = (unsigned short*)p; p = alignp(p + DD * DD * 2, 256);
    unsigned short* wbt2 = (unsigned short*)p; p = alignp(p + DD * DD * 2, 256);
    unsigned char* epos8 = (unsigned char*)p;  p = alignp(p + EE, 256);

    // Aliases (CH*NP8 = 256*50000 = 12,800,000 B = exactly NN*DD*2):
    //  histI8 -> hb2: choff dead after fill_kernel; fused<1> writes hb2 after fill.  OK
    //  histO8 -> hb1: histO dead after sum_kernel; scanC writes hb1 (cast) after sum. OK
    unsigned char* histI8 = (unsigned char*)hb2;
    unsigned char* histO8 = (unsigned char*)hb1;

    hist_kernel<<<CH, 256, 0, stream>>>(src, dst, epos8,
                                        (unsigned int*)histI8, (unsigned int*)histO8);
    sum_kernel<<<SCAN_BLOCKS, 256, 0, stream>>>(histI8, histO8, cntI, iso, isi, bsum);
    scanC_kernel<<<SCAN_BLOCKS, 256, 0, stream>>>(cntI, bsum, rowptr, features, iso, hb1);
    fill_kernel<<<(EE + 255) / 256, 256, 0, stream>>>(src, dst, epos8, histI8,
                                                      rowptr, csr, W1, W2, wbt1, wbt2);

    const int fblocks = NN / ROWS;  // 3125 exactly
    // layer 1: hb1 -> hb2 (bf16, iso-prescaled)
    fused_layer<1><<<fblocks, 256, 0, stream>>>(hb1, csr, rowptr, isi, iso,
                                                wbt1, b1, g1, be1, nullptr, hb2);
    // layer 2: hb2 -> out (fp32)
    fused_layer<0><<<fblocks, 256, 0, stream>>>(hb2, csr, rowptr, isi, iso,
                                                wbt2, b2, g2, be2, out, nullptr);
}

// Round 13
// 232.853 us; speedup vs baseline: 1.2726x; 1.0965x over previous
//
#include <hip/hip_runtime.h>
#include <stdint.h>

#define NN 50000
#define DD 128
#define EE 800000
#define LN_EPS 1e-5f
#define SCAN_BLOCKS ((NN + 255) / 256)   // 196
#define ROWS 16                          // nodes per fused block (50000 = 3125 * 16)
#define ASTRIDE 136                      // LDS A stride in bf16 elems

#define CH 256                           // edge chunks (one block each)
#define EC (EE / CH)                     // 3125 edges/chunk
#define NP8 50000                        // bytes per chunk hist (u8 per node)
#define NW (NP8 / 4)                     // 12500 u32 words

typedef __attribute__((ext_vector_type(8))) short bf8_t;   // 8 bf16 (MFMA A/B frag)
typedef __attribute__((ext_vector_type(4))) float f32x4;   // MFMA C/D frag

// round-to-nearest-even fp32 -> bf16 bits
static __device__ __forceinline__ unsigned short f2bf(float f) {
    unsigned u = __float_as_uint(f);
    u += 0x7FFFu + ((u >> 16) & 1u);
    return (unsigned short)(u >> 16);
}

#define BF16ACC(u) do { \
    acc[0] += __uint_as_float((u).x << 16); \
    acc[1] += __uint_as_float((u).x & 0xffff0000u); \
    acc[2] += __uint_as_float((u).y << 16); \
    acc[3] += __uint_as_float((u).y & 0xffff0000u); \
    acc[4] += __uint_as_float((u).z << 16); \
    acc[5] += __uint_as_float((u).z & 0xffff0000u); \
    acc[6] += __uint_as_float((u).w << 16); \
    acc[7] += __uint_as_float((u).w & 0xffff0000u); \
} while (0)

// ---------------- chunk histograms: dst + src counted in ONE edge pass (100 KB LDS) ----------------
__global__ __launch_bounds__(256) void hist_kernel(
    const int* __restrict__ src, const int* __restrict__ dst,
    unsigned int* __restrict__ histI, unsigned int* __restrict__ histO) {
    __shared__ unsigned int lhI[NW];   // 50 KB
    __shared__ unsigned int lhO[NW];   // 50 KB
    int tid = threadIdx.x;
    int c = blockIdx.x;
    int e0 = c * EC, e1 = e0 + EC;

    for (int w = tid; w < NW; w += 256) { lhI[w] = 0; lhO[w] = 0; }
    __syncthreads();
    for (int e = e0 + tid; e < e1; e += 256) {
        int d = dst[e];
        int s = src[e];
        atomicAdd(&lhI[d >> 2], 1u << ((d & 3) * 8));
        atomicAdd(&lhO[s >> 2], 1u << ((s & 3) * 8));
    }
    __syncthreads();
    {
        unsigned int* oi = histI + (size_t)c * NW;
        unsigned int* oo = histO + (size_t)c * NW;
        for (int w = tid; w < NW; w += 256) { oi[w] = lhI[w]; oo[w] = lhO[w]; }
    }
}

// ---------------- sum chunk hists -> cntI/choff(in-place)/iso/isi/bsum ----------------
__global__ __launch_bounds__(256) void sum_kernel(
    unsigned char* __restrict__ histI8,          // in-place -> choff8
    const unsigned char* __restrict__ histO8,
    int* __restrict__ cntI, float* __restrict__ iso, float* __restrict__ isi,
    int* __restrict__ bsum) {
    __shared__ int s[256];
    int tid = threadIdx.x;
    int n = blockIdx.x * 256 + tid;

    int ci = 0, co = 0;
    if (n < NN) {
#pragma unroll 8
        for (int c = 0; c < CH; c++) {
            size_t idx = (size_t)c * NP8 + n;
            unsigned char v = histI8[idx];
            histI8[idx] = (unsigned char)ci;   // choff8[c][n] = prefix (max in-deg << 256)
            ci += v;
            co += histO8[idx];
        }
        iso[n] = rsqrtf(fmaxf((float)co, 1.0f));
        isi[n] = rsqrtf(fmaxf((float)ci, 1.0f));
        cntI[n] = ci;
    }
    s[tid] = (n < NN) ? ci : 0;
    __syncthreads();
    for (int off = 128; off > 0; off >>= 1) {
        if (tid < off) s[tid] += s[tid + off];
        __syncthreads();
    }
    if (tid == 0) bsum[blockIdx.x] = s[0];
}

// ---------------- rowptr (local bsum prefix) + feature cast (hb1 = bf16(feat*iso)) ----------------
__global__ __launch_bounds__(256) void scanC_kernel(
    const int* __restrict__ cnt, const int* __restrict__ bsum,
    int* __restrict__ rowptr,
    const float* __restrict__ feat, const float* __restrict__ iso,
    unsigned short* __restrict__ hb) {
    __shared__ int s[256];
    __shared__ int base_s;
    __shared__ float iso_s[256];
    int tid = threadIdx.x;
    int i = blockIdx.x * 256 + tid;

    int bv = (tid < SCAN_BLOCKS && tid < blockIdx.x) ? bsum[tid] : 0;
    s[tid] = bv;
    __syncthreads();
    for (int off = 128; off > 0; off >>= 1) {
        if (tid < off) s[tid] += s[tid + off];
        __syncthreads();
    }
    if (tid == 0) base_s = s[0];
    __syncthreads();
    int base = base_s;

    iso_s[tid] = (i < NN) ? iso[i] : 1.f;
    __syncthreads();

    int v = (i < NN) ? cnt[i] : 0;
    s[tid] = v;
    __syncthreads();
    for (int off = 1; off < 256; off <<= 1) {
        int t = (tid >= off) ? s[tid - off] : 0;
        __syncthreads();
        s[tid] += t;
        __syncthreads();
    }
    if (i < NN) rowptr[i] = base + s[tid] - v;  // exclusive
    if (blockIdx.x == 0 && tid == 0) rowptr[NN] = EE;

    // cast this block's 256 rows: 8 rows x 32 lanes (coalesced float4)
    int rr = tid >> 5;
    int q = tid & 31;
    int row0 = blockIdx.x * 256;
#pragma unroll 4
    for (int it = 0; it < 32; it++) {
        int r = it * 8 + rr;
        int row = row0 + r;
        if (row < NN) {
            float sc = iso_s[r];
            float4 fv = ((const float4*)feat)[(size_t)row * 32 + q];
            ushort4 o;
            o.x = f2bf(fv.x * sc); o.y = f2bf(fv.y * sc);
            o.z = f2bf(fv.z * sc); o.w = f2bf(fv.w * sc);
            ((ushort4*)hb)[(size_t)row * 32 + q] = o;
        }
    }
}

// ---------------- CSR fill: one block per chunk; choff slice + recomputed epos in LDS ----------
// Removes the 800k random global choff reads (51 MB of 64B lines). epos is recomputed via the
// same LDS histogram trick — any within-bucket permutation is valid (gather is order-invariant).
__global__ __launch_bounds__(256) void fill_kernel(
    const int* __restrict__ src, const int* __restrict__ dst,
    const unsigned char* __restrict__ choff8,
    const int* __restrict__ rowptr, int* __restrict__ csr,
    const float* __restrict__ W1, const float* __restrict__ W2,
    unsigned short* __restrict__ wbt1, unsigned short* __restrict__ wbt2) {
    __shared__ unsigned int lh[NW];        // 50 KB counting
    __shared__ unsigned char lco[NP8];     // 50 KB choff slice
    int tid = threadIdx.x;
    int c = blockIdx.x;
    int e0 = c * EC, e1 = e0 + EC;

    {
        const unsigned int* ci = (const unsigned int*)(choff8 + (size_t)c * NP8);
        for (int w = tid; w < NW; w += 256) { lh[w] = 0; ((unsigned int*)lco)[w] = ci[w]; }
    }
    __syncthreads();
    for (int e = e0 + tid; e < e1; e += 256) {
        int d = dst[e];
        int f = (d & 3) * 8;
        unsigned old = atomicAdd(&lh[d >> 2], 1u << f);
        int epos = (int)((old >> f) & 0xffu);
        csr[rowptr[d] + (int)lco[d] + epos] = src[e];
    }
    // first 128 blocks also produce wbt[n][k] = bf16(W[k][n])
    if (c < 128) {
        int idx = (c & 63) * 256 + tid;    // 0..16383 = k*128+n
        const float* W = (c < 64) ? W1 : W2;
        unsigned short* wt = (c < 64) ? wbt1 : wbt2;
        int k = idx >> 7, n = idx & 127;
        wt[n * 128 + k] = f2bf(W[idx]);
    }
}

// ---------------- fused: gather(bf16, masked 8-unroll) -> bf16 LDS -> MFMA -> LN -> ReLU ------
// ROWS=16, 3125 blocks. Gather keeps 8 loads in flight for ALL edges: indices clamped to
// end-1, invalid lanes AND-masked to 0x0 (= +0.0f bf16 pair) — kills the scalar-tail
// serialization (E[deg mod 8] ~ 3.5 edges at 1 load in flight dominated the old loop).
template <int OUTMODE>
__global__ __launch_bounds__(256) void fused_layer(
    const unsigned short* __restrict__ hb, const int* __restrict__ csr,
    const int* __restrict__ rowptr, const float* __restrict__ isi,
    const float* __restrict__ iso,
    const unsigned short* __restrict__ wbt, const float* __restrict__ b,
    const float* __restrict__ g, const float* __restrict__ be,
    float* __restrict__ outf, unsigned short* __restrict__ outb) {
    __shared__ unsigned short Asb[ROWS][ASTRIDE];   // 4352 B
    __shared__ float redS[4][16], redSS[4][16];     // 512 B

    int tid = threadIdx.x;
    int node0 = blockIdx.x * ROWS;
    int w = tid >> 6;            // wave 0..3
    int lane = tid & 63;
    int quad = lane >> 4;        // 0..3
    int l = lane & 15;           // 0..15

    // ---- phase 1: gather (subgroup tid>>4 owns row tid>>4) ----
    {
        int r = tid >> 4;        // 0..15
        int n = node0 + r;
        float acc[8];
#pragma unroll
        for (int i = 0; i < 8; i++) acc[i] = 0.f;
        int beg = rowptr[n];
        int end = rowptr[n + 1];
        for (int j = beg; j < end; j += 8) {
            uint4 u[8];
            unsigned m[8];
#pragma unroll
            for (int i = 0; i < 8; i++) {
                int t = j + i;
                int tc = (t < end) ? t : (end - 1);
                m[i] = (t < end) ? 0xffffffffu : 0u;
                int s = csr[tc];
                u[i] = ((const uint4*)(hb + (size_t)s * DD))[l];
            }
#pragma unroll
            for (int i = 0; i < 8; i++) {
                uint4 v = u[i];
                v.x &= m[i]; v.y &= m[i]; v.z &= m[i]; v.w &= m[i];
                BF16ACC(v);
            }
        }
        uint4 pk;
        pk.x = (unsigned)f2bf(acc[0]) | ((unsigned)f2bf(acc[1]) << 16);
        pk.y = (unsigned)f2bf(acc[2]) | ((unsigned)f2bf(acc[3]) << 16);
        pk.z = (unsigned)f2bf(acc[4]) | ((unsigned)f2bf(acc[5]) << 16);
        pk.w = (unsigned)f2bf(acc[6]) | ((unsigned)f2bf(acc[7]) << 16);
        *(uint4*)&Asb[r][l * 8] = pk;
    }
    __syncthreads();

    // ---- phase 2: MFMA GEMM (16 rows x 128 cols; wave w -> cols [w*32, w*32+32)) ----
    bf8_t af[4];
#pragma unroll
    for (int kb = 0; kb < 4; kb++)
        af[kb] = *(bf8_t*)&Asb[l][kb * 32 + quad * 8];

    f32x4 acc[2];
#pragma unroll
    for (int tc = 0; tc < 2; tc++) acc[tc] = (f32x4){0.f, 0.f, 0.f, 0.f};

#pragma unroll
    for (int tc = 0; tc < 2; tc++) {
        int n = w * 32 + tc * 16 + l;   // output column
#pragma unroll
        for (int kb = 0; kb < 4; kb++) {
            bf8_t bfr = *(const bf8_t*)&wbt[(size_t)n * 128 + kb * 32 + quad * 8];
            acc[tc] = __builtin_amdgcn_mfma_f32_16x16x32_bf16(af[kb], bfr, acc[tc], 0, 0, 0);
        }
    }

    // ---- epilogue: *isi, +b, LN, ReLU, store ----
    float bb[2], ggv[2], bev[2];
    int cbase = w * 32 + l;
#pragma unroll
    for (int tc = 0; tc < 2; tc++) {
        int c = cbase + tc * 16;
        bb[tc] = b[c]; ggv[tc] = g[c]; bev[tc] = be[c];
    }

    float s[4], ss[4];
#pragma unroll
    for (int i = 0; i < 4; i++) {
        int n = node0 + quad * 4 + i;
        float isin = isi[n];
        s[i] = 0.f; ss[i] = 0.f;
#pragma unroll
        for (int tc = 0; tc < 2; tc++) {
            float v = acc[tc][i] * isin + bb[tc];
            acc[tc][i] = v;
            s[i] += v; ss[i] += v * v;
        }
    }
#pragma unroll
    for (int i = 0; i < 4; i++) {
#pragma unroll
        for (int m = 1; m <= 8; m <<= 1) {
            s[i] += __shfl_xor(s[i], m);
            ss[i] += __shfl_xor(ss[i], m);
        }
    }
    if (l == 0) {
#pragma unroll
        for (int i = 0; i < 4; i++) {
            redS[w][quad * 4 + i] = s[i];
            redSS[w][quad * 4 + i] = ss[i];
        }
    }
    __syncthreads();

#pragma unroll
    for (int i = 0; i < 4; i++) {
        int r = quad * 4 + i;
        float S  = redS[0][r] + redS[1][r] + redS[2][r] + redS[3][r];
        float SS = redSS[0][r] + redSS[1][r] + redSS[2][r] + redSS[3][r];
        float mu = S * (1.f / 128.f);
        float var = SS * (1.f / 128.f) - mu * mu;
        float rstd = rsqrtf(var + LN_EPS);
        int n = node0 + r;
        float isov = (OUTMODE == 1) ? iso[n] : 0.f;
        size_t base = (size_t)n * DD;
#pragma unroll
        for (int tc = 0; tc < 2; tc++) {
            float o = fmaxf((acc[tc][i] - mu) * rstd * ggv[tc] + bev[tc], 0.f);
            int c = cbase + tc * 16;
            if (OUTMODE == 0) {
                outf[base + c] = o;
            } else {
                outb[base + c] = f2bf(o * isov);
            }
        }
    }
}

static inline char* alignp(char* p, size_t a) {
    return (char*)(((uintptr_t)p + a - 1) & ~(uintptr_t)(a - 1));
}

extern "C" void kernel_launch(void* const* d_in, const int* in_sizes, int n_in,
                              void* d_out, int out_size, void* d_ws, size_t ws_size,
                              hipStream_t stream) {
    const float* features = (const float*)d_in[0];
    const int*   src      = (const int*)d_in[1];
    const int*   dst      = (const int*)d_in[2];
    const float* W1  = (const float*)d_in[3];
    const float* b1  = (const float*)d_in[4];
    const float* g1  = (const float*)d_in[5];
    const float* be1 = (const float*)d_in[6];
    const float* W2  = (const float*)d_in[7];
    const float* b2  = (const float*)d_in[8];
    const float* g2  = (const float*)d_in[9];
    const float* be2 = (const float*)d_in[10];
    float* out = (float*)d_out;

    // workspace layout (256B-aligned slices)
    char* p = (char*)d_ws;
    int* cntI = (int*)p;                 p = alignp(p + NN * 4, 256);
    int* rowptr = (int*)p;               p = alignp(p + (NN + 1) * 4, 256);
    int* bsum = (int*)p;                 p = alignp(p + SCAN_BLOCKS * 4, 256);
    int* csr = (int*)p;                  p = alignp(p + (size_t)EE * 4, 256);
    float* iso = (float*)p;              p = alignp(p + NN * 4, 256);
    float* isi = (float*)p;              p = alignp(p + NN * 4, 256);
    unsigned short* hb1 = (unsigned short*)p;  p = alignp(p + (size_t)NN * DD * 2, 256);
    unsigned short* hb2 = (unsigned short*)p;  p = alignp(p + (size_t)NN * DD * 2, 256);
    unsigned short* wbt1 = (unsigned short*)p; p = alignp(p + DD * DD * 2, 256);
    unsigned short* wbt2 = (unsigned short*)p; p = alignp(p + DD * DD * 2, 256);

    // Aliases (CH*NP8 = 12,800,000 B = exactly NN*DD*2):
    //  histI8 -> hb2: choff dead after fill_kernel; fused<1> writes hb2 after fill.  OK
    //  histO8 -> hb1: histO dead after sum_kernel; scanC writes hb1 (cast) after sum. OK
    unsigned char* histI8 = (unsigned char*)hb2;
    unsigned char* histO8 = (unsigned char*)hb1;

    hist_kernel<<<CH, 256, 0, stream>>>(src, dst,
                                        (unsigned int*)histI8, (unsigned int*)histO8);
    sum_kernel<<<SCAN_BLOCKS, 256, 0, stream>>>(histI8, histO8, cntI, iso, isi, bsum);
    scanC_kernel<<<SCAN_BLOCKS, 256, 0, stream>>>(cntI, bsum, rowptr, features, iso, hb1);
    fill_kernel<<<CH, 256, 0, stream>>>(src, dst, histI8, rowptr, csr,
                                        W1, W2, wbt1, wbt2);

    const int fblocks = NN / ROWS;  // 3125 exactly
    // layer 1: hb1 -> hb2 (bf16, iso-prescaled)
    fused_layer<1><<<fblocks, 256, 0, stream>>>(hb1, csr, rowptr, isi, iso,
                                                wbt1, b1, g1, be1, nullptr, hb2);
    // layer 2: hb2 -> out (fp32)
    fused_layer<0><<<fblocks, 256, 0, stream>>>(hb2, csr, rowptr, isi, iso,
                                                wbt2, b2, g2, be2, out, nullptr);
}